// Round 7
// baseline (71.206 us; speedup 1.0000x reference)
//
#include <hip/hip_runtime.h>
#include <math.h>

// Chamfer distance: B=16, N=M=2048, D=3, fp32. Two kernels, two graph nodes.
// Stage 1 (512 blocks, 2/CU): block = (combo, slice, src-half). Scans a
//   256-pt opposing slice (SoA LDS, broadcast ds_read_b128) for 1024 src pts
//   (4 contiguous/thread), packed fp32 fma + min3 -> 2 VALU ops/pair.
//   Partial minima of s = |y|^2 - 2 x.y -> d_ws (2 MB, float4 stores).
//   Block 0 zeroes out[0] (kernel-boundary ordering covers stage 2).
// Stage 2 (256 blocks): min over 8 slices, add |x|^2, block-sum, one
//   atomicAdd per block. No tickets/fences (R5 showed the weak-tail cost).

typedef float v2f __attribute__((ext_vector_type(2)));

#define NPTS    2048
#define NCOMBO  32           // 2 dirs x 16 batches
#define KSLICE  8
#define SLICE   256          // NPTS / KSLICE
#define SPT     4            // contiguous src points per thread (stage 1)

__device__ __forceinline__ v2f pkfma(v2f a, v2f b, v2f c) {
#if __has_builtin(__builtin_elementwise_fma)
    return __builtin_elementwise_fma(a, b, c);
#else
    v2f d; d.x = fmaf(a.x, b.x, c.x); d.y = fmaf(a.y, b.y, c.y); return d;
#endif
}

__global__ __launch_bounds__(256, 2) void chamfer_partial(
    const float* __restrict__ preds,
    const float* __restrict__ tgts,
    float* __restrict__ partial,
    float* __restrict__ out)
{
    __shared__ __align__(16) float qx[SLICE];
    __shared__ __align__(16) float qy[SLICE];
    __shared__ __align__(16) float qz[SLICE];
    __shared__ __align__(16) float qw[SLICE];

    const int bid   = blockIdx.x;            // 0..511
    const int combo = bid & (NCOMBO - 1);    // inner: spreads combos across XCDs
    const int rest  = bid >> 5;              // 0..15
    const int slice = rest >> 1;             // 0..7
    const int half  = rest & 1;              // src half
    const int dir   = combo >> 4;
    const int b     = combo & 15;

    if (bid == 0 && threadIdx.x == 0) out[0] = 0.0f;

    const float* src = (dir ? tgts : preds) + (size_t)b * NPTS * 3;
    const float* opp = (dir ? preds : tgts) + (size_t)b * NPTS * 3;

    // Stage opposing slice (SoA, |y|^2 in qw)
    {
        const int jj = slice * SLICE + threadIdx.x;
        const float y0 = opp[3 * jj + 0];
        const float y1 = opp[3 * jj + 1];
        const float y2 = opp[3 * jj + 2];
        qx[threadIdx.x] = y0;
        qy[threadIdx.x] = y1;
        qz[threadIdx.x] = y2;
        qw[threadIdx.x] = y0 * y0 + y1 * y1 + y2 * y2;
    }

    // 4 contiguous src points per thread: floats [base3, base3+12)
    const int i0 = half * 1024 + SPT * threadIdx.x;
    const float4 r0 = *(const float4*)&src[3 * i0 + 0];
    const float4 r1 = *(const float4*)&src[3 * i0 + 4];
    const float4 r2 = *(const float4*)&src[3 * i0 + 8];
    // points: (r0.x r0.y r0.z) (r0.w r1.x r1.y) (r1.z r1.w r2.x) (r2.y r2.z r2.w)
    v2f nn0[SPT], nn1[SPT], nn2[SPT];
    {
        const float px[SPT] = {r0.x, r0.w, r1.z, r2.y};
        const float py[SPT] = {r0.y, r1.x, r1.w, r2.z};
        const float pz[SPT] = {r0.z, r1.y, r2.x, r2.w};
        #pragma unroll
        for (int k = 0; k < SPT; k++) {
            const float a0 = -2.0f * px[k];
            const float a1 = -2.0f * py[k];
            const float a2 = -2.0f * pz[k];
            nn0[k] = (v2f){a0, a0};
            nn1[k] = (v2f){a1, a1};
            nn2[k] = (v2f){a2, a2};
        }
    }
    float m[SPT];
    #pragma unroll
    for (int k = 0; k < SPT; k++) m[k] = INFINITY;

    __syncthreads();

    #pragma unroll 4
    for (int jg = 0; jg < SLICE / 4; jg++) {
        const float4 X = *(const float4*)&qx[4 * jg];
        const float4 Y = *(const float4*)&qy[4 * jg];
        const float4 Z = *(const float4*)&qz[4 * jg];
        const float4 W = *(const float4*)&qw[4 * jg];
        const v2f Xa = {X.x, X.y}, Xb = {X.z, X.w};
        const v2f Ya = {Y.x, Y.y}, Yb = {Y.z, Y.w};
        const v2f Za = {Z.x, Z.y}, Zb = {Z.z, Z.w};
        const v2f Wa = {W.x, W.y}, Wb = {W.z, W.w};
        #pragma unroll
        for (int k = 0; k < SPT; k++) {
            const v2f sa = pkfma(nn0[k], Xa, pkfma(nn1[k], Ya, pkfma(nn2[k], Za, Wa)));
            m[k] = fminf(fminf(m[k], sa.x), sa.y);        // v_min3_f32
            const v2f sb = pkfma(nn0[k], Xb, pkfma(nn1[k], Yb, pkfma(nn2[k], Zb, Wb)));
            m[k] = fminf(fminf(m[k], sb.x), sb.y);        // v_min3_f32
        }
    }

    float* pp = partial + ((size_t)combo * KSLICE + slice) * NPTS + i0;
    *(float4*)pp = make_float4(m[0], m[1], m[2], m[3]);   // coalesced 16B store
}

__global__ __launch_bounds__(256) void chamfer_reduce(
    const float* __restrict__ preds,
    const float* __restrict__ tgts,
    const float* __restrict__ partial,
    float* __restrict__ out)
{
    __shared__ float wsum[4];

    const int idx   = blockIdx.x * 256 + threadIdx.x;   // 0..65535
    const int combo = idx >> 11;                        // uniform per block
    const int i     = idx & (NPTS - 1);
    const int dir   = combo >> 4;
    const int b     = combo & 15;

    const float* src = (dir ? tgts : preds) + (size_t)b * NPTS * 3;
    const float x0 = src[3 * i + 0];
    const float x1 = src[3 * i + 1];
    const float x2 = src[3 * i + 2];
    const float xx = x0 * x0 + x1 * x1 + x2 * x2;

    const float* pp = partial + (size_t)combo * KSLICE * NPTS + i;
    float mn = pp[0];
    #pragma unroll
    for (int s = 1; s < KSLICE; s++)
        mn = fminf(mn, pp[(size_t)s * NPTS]);

    float val = xx + mn;

    #pragma unroll
    for (int off = 32; off > 0; off >>= 1)
        val += __shfl_down(val, off, 64);

    const int lane = threadIdx.x & 63;
    const int wid  = threadIdx.x >> 6;
    if (lane == 0) wsum[wid] = val;
    __syncthreads();
    if (threadIdx.x == 0)
        atomicAdd(out, wsum[0] + wsum[1] + wsum[2] + wsum[3]);
}

extern "C" void kernel_launch(void* const* d_in, const int* in_sizes, int n_in,
                              void* d_out, int out_size, void* d_ws, size_t ws_size,
                              hipStream_t stream) {
    const float* preds = (const float*)d_in[0];
    const float* tgts  = (const float*)d_in[1];
    float* out     = (float*)d_out;
    float* partial = (float*)d_ws;   // 32 combos x 8 slices x 2048 = 2 MB

    chamfer_partial<<<NCOMBO * KSLICE * 2, 256, 0, stream>>>(preds, tgts, partial, out);
    chamfer_reduce<<<(2 * 16 * NPTS) / 256, 256, 0, stream>>>(preds, tgts, partial, out);
}